// Round 11
// baseline (272.505 us; speedup 1.0000x reference)
//
#include <hip/hip_runtime.h>

// points [B=32, N=8192, 3] f32. FPS -> K=128 centers/batch (start 0);
// KNN -> P=32 nearest per center, ascending d2, ties by lower index.
// d_out is FLOAT32, flat concat: [idx B*K*P | centers B*K*3].
#define BB 32
#define NN 8192
#define KK 128
#define PP 32
#define IDX_COUNT (BB * KK * PP)   // 131072

// ---- contract-off packed helpers (header operators compile under
// -ffp-contract=fast -> silent FMA would break numpy bit-parity) ----------
__device__ __forceinline__ float2 f2sub(float2 a, float2 b) {
#pragma clang fp contract(off)
    float2 r; r.x = a.x - b.x; r.y = a.y - b.y; return r;
}
__device__ __forceinline__ float2 f2mul(float2 a, float2 b) {
#pragma clang fp contract(off)
    float2 r; r.x = a.x * b.x; r.y = a.y * b.y; return r;
}
__device__ __forceinline__ float2 f2add(float2 a, float2 b) {
#pragma clang fp contract(off)
    float2 r; r.x = a.x + b.x; r.y = a.y + b.y; return r;
}

// ---- DPP wave64 u64 reduce, IDEMPOTENT op only (min/max), lane 63 result.
// NOTE (R10 post-mortem): this 6-stage pattern is proven (R9 pass) for
// idempotent ops ONLY — it guarantees coverage, not disjointness. Do NOT
// use it for non-idempotent merges (e.g. keep-2-smallest): duplicate
// accumulation corrupts the result (R10 failure).
#define DPP_RED_U64(v, CMP)                                                   \
    {                                                                         \
        _Pragma("unroll")                                                     \
        for (int s = 0; s < 6; ++s) {                                         \
            unsigned lo = (unsigned)v, hi = (unsigned)(v >> 32);              \
            unsigned slo, shi;                                                \
            switch (s) {                                                      \
            case 0:                                                           \
                slo = (unsigned)__builtin_amdgcn_update_dpp((int)lo, (int)lo, 0x111, 0xf, 0xf, false); \
                shi = (unsigned)__builtin_amdgcn_update_dpp((int)hi, (int)hi, 0x111, 0xf, 0xf, false); break; \
            case 1:                                                           \
                slo = (unsigned)__builtin_amdgcn_update_dpp((int)lo, (int)lo, 0x112, 0xf, 0xf, false); \
                shi = (unsigned)__builtin_amdgcn_update_dpp((int)hi, (int)hi, 0x112, 0xf, 0xf, false); break; \
            case 2:                                                           \
                slo = (unsigned)__builtin_amdgcn_update_dpp((int)lo, (int)lo, 0x114, 0xf, 0xf, false); \
                shi = (unsigned)__builtin_amdgcn_update_dpp((int)hi, (int)hi, 0x114, 0xf, 0xf, false); break; \
            case 3:                                                           \
                slo = (unsigned)__builtin_amdgcn_update_dpp((int)lo, (int)lo, 0x118, 0xf, 0xf, false); \
                shi = (unsigned)__builtin_amdgcn_update_dpp((int)hi, (int)hi, 0x118, 0xf, 0xf, false); break; \
            case 4:                                                           \
                slo = (unsigned)__builtin_amdgcn_update_dpp((int)lo, (int)lo, 0x142, 0xf, 0xf, false); \
                shi = (unsigned)__builtin_amdgcn_update_dpp((int)hi, (int)hi, 0x142, 0xf, 0xf, false); break; \
            default:                                                          \
                slo = (unsigned)__builtin_amdgcn_update_dpp((int)lo, (int)lo, 0x143, 0xf, 0xf, false); \
                shi = (unsigned)__builtin_amdgcn_update_dpp((int)hi, (int)hi, 0x143, 0xf, 0xf, false); break; \
            }                                                                 \
            const unsigned long long sv = ((unsigned long long)shi << 32) | slo; \
            if (sv CMP v) v = sv;                                             \
        }                                                                     \
    }

__device__ __forceinline__ unsigned long long readlane63_u64(unsigned long long v) {
    const unsigned lo = (unsigned)__builtin_amdgcn_readlane((int)(unsigned)v, 63);
    const unsigned hi = (unsigned)__builtin_amdgcn_readlane((int)(unsigned)(v >> 32), 63);
    return ((unsigned long long)hi << 32) | lo;
}

// ---------------------------------------------------------------------------
// FPS: one block per batch, 512 threads, 16 pts/thread as float2 PAIRS
// (v_pk_* packed f32 — per-half rounding identical to scalar, parity safe)
// + full cloud in LDS for winner-coord broadcast. Scan: packed d update,
// value-only fmax chain; idx recovered post-loop by descending bit-equal
// match (numpy first-index tie-break; d>=0 so no -0.0/==-ambiguity).
// Cross-lane/wave: u64 (val,~idx) DPP max + 8-slot LDS merge, 1 barrier/step.
// Centers buffered in LDS; bulk write at end. Mirrors points to d_ws
// float4(x,y,z,pp) for KNN.
// ---------------------------------------------------------------------------
__global__ __launch_bounds__(512) void fps_kernel(
    const float* __restrict__ pts, float* __restrict__ out,
    float4* __restrict__ wsp)                    // may be null
{
#pragma clang fp contract(off)
    const int b = blockIdx.x;
    const int t = threadIdx.x;
    const float* p = pts + (size_t)b * NN * 3;

    __shared__ float pts3[NN * 3];               // 96 KB
    __shared__ float cbuf[KK * 3];
    __shared__ unsigned long long wk[2][8];

    float2 px[8], py[8], pz[8], mind[8];         // pair j: idx t+(2j)*512, t+(2j+1)*512
#pragma unroll
    for (int j = 0; j < 8; ++j) {
#pragma unroll
        for (int h = 0; h < 2; ++h) {
            const int idx = t + (2 * j + h) * 512;
            const float x = p[idx * 3 + 0], y = p[idx * 3 + 1], z = p[idx * 3 + 2];
            if (h == 0) { px[j].x = x; py[j].x = y; pz[j].x = z; mind[j].x = __builtin_inff(); }
            else        { px[j].y = x; py[j].y = y; pz[j].y = z; mind[j].y = __builtin_inff(); }
            pts3[idx * 3 + 0] = x; pts3[idx * 3 + 1] = y; pts3[idx * 3 + 2] = z;
            if (wsp) wsp[(size_t)b * NN + idx] =
                make_float4(x, y, z, (x * x + y * y) + z * z);
        }
    }
    __syncthreads();

    float lx = pts3[0], ly = pts3[1], lz = pts3[2];   // start center = pt 0
    if (t == 0) { cbuf[0] = lx; cbuf[1] = ly; cbuf[2] = lz; }
    const int lane = t & 63, wid = t >> 6;

    for (int k = 0; k < KK - 1; ++k) {          // 127 steps; last argmax unused
        const float2 l2x = make_float2(lx, lx);
        const float2 l2y = make_float2(ly, ly);
        const float2 l2z = make_float2(lz, lz);
        float bestv = -1.0f;
#pragma unroll
        for (int j = 0; j < 8; ++j) {
            const float2 dx = f2sub(px[j], l2x);
            const float2 dy = f2sub(py[j], l2y);
            const float2 dz = f2sub(pz[j], l2z);
            // d = (dx*dx + dy*dy) + dz*dz, packed, no contraction
            const float2 d = f2add(f2add(f2mul(dx, dx), f2mul(dy, dy)),
                                   f2mul(dz, dz));
            mind[j].x = fminf(mind[j].x, d.x);
            mind[j].y = fminf(mind[j].y, d.y);
            bestv = fmaxf(bestv, fmaxf(mind[j].x, mind[j].y));
        }
        // recover lowest idx achieving bestv (descending overwrite)
        unsigned bidx = 0;
#pragma unroll
        for (int s = 15; s >= 0; --s) {
            const float v = (s & 1) ? mind[s >> 1].y : mind[s >> 1].x;
            if (v == bestv) bidx = (unsigned)(t + s * 512);
        }
        union { float f; unsigned u; } cv; cv.f = bestv;  // >= 0
        unsigned long long key = ((unsigned long long)cv.u << 32)
                               | (0xFFFFFFFFu - bidx);    // low-idx tie-break
        DPP_RED_U64(key, >);                     // lane 63 authoritative
        if (lane == 63) wk[k & 1][wid] = key;
        __syncthreads();
        unsigned long long w = wk[k & 1][0];
#pragma unroll
        for (int i = 1; i < 8; ++i) {
            const unsigned long long o = wk[k & 1][i];
            if (o > w) w = o;
        }
        const unsigned last = 0xFFFFFFFFu - (unsigned)(w & 0xFFFFFFFFu);
        lx = pts3[last * 3 + 0];                 // broadcast reads
        ly = pts3[last * 3 + 1];
        lz = pts3[last * 3 + 2];
        if (t == 0) {
            cbuf[(k + 1) * 3 + 0] = lx;
            cbuf[(k + 1) * 3 + 1] = ly;
            cbuf[(k + 1) * 3 + 2] = lz;
        }
    }
    __syncthreads();
    if (t < KK * 3)
        out[IDX_COUNT + b * (KK * 3) + t] = cbuf[t];
}

// ---------------------------------------------------------------------------
// KNN: 8 blocks/batch, 1024 threads (16 waves = 4/SIMD), full cloud in
// 128 KB LDS as float4(x,y,z,pp); ONE center per wave. d2 = (cc+pp) - 2*dot,
// no FMA, -0.0 canonicalized — numpy bit-parity. Per lane: 4-deep sorted
// u64 cache; extraction = 32 rounds of IDEMPOTENT DPP min-reduce + readlane
// (R9-proven; the 2-winner pair-merge variant is NOT disjointness-safe,
// see R10 post-mortem). Refill (cache empty, ~10%/center) rescans LDS with
// kk>best filter — exact. u64 keys (ordered-d2, idx): unique; ascending ==
// reference order incl. lower-index tie-break.
// ---------------------------------------------------------------------------
#define CACHE_INS(kk, m1, m2, m3, m4)                                   \
    {                                                                   \
        const bool c1 = (kk) < m1, c2 = (kk) < m2,                      \
                   c3 = (kk) < m3, c4 = (kk) < m4;                      \
        m4 = c3 ? m3 : (c4 ? (kk) : m4);                                \
        m3 = c2 ? m2 : (c3 ? (kk) : m3);                                \
        m2 = c1 ? m1 : (c2 ? (kk) : m2);                                \
        m1 = c1 ? (kk) : m1;                                            \
    }

template <bool USE_WS>
__global__ __launch_bounds__(1024) void knn_kernel(
    const float* __restrict__ pts, const float4* __restrict__ wsp_all,
    float* __restrict__ out)
{
#pragma clang fp contract(off)
    const int t = threadIdx.x, lane = t & 63, wid = t >> 6;
    const int blk = blockIdx.x;              // 0..255
    const int b = blk >> 3;                  // batch
    const int bk = b * KK + (blk & 7) * 16 + wid;   // this wave's center

    __shared__ float4 sp[NN];                // 128 KB
    if (USE_WS) {
        const float4* wsp = wsp_all + (size_t)b * NN;
#pragma unroll
        for (int i = 0; i < 8; ++i) {
            const int idx = t + i * 1024;
            sp[idx] = wsp[idx];
        }
    } else {
        const float* p = pts + (size_t)b * NN * 3;
#pragma unroll
        for (int i = 0; i < 8; ++i) {
            const int idx = t + i * 1024;
            const float x = p[idx * 3 + 0], y = p[idx * 3 + 1], z = p[idx * 3 + 2];
            sp[idx] = make_float4(x, y, z, (x * x + y * y) + z * z);
        }
    }

    const float cx = out[IDX_COUNT + bk * 3 + 0];
    const float cy = out[IDX_COUNT + bk * 3 + 1];
    const float cz = out[IDX_COUNT + bk * 3 + 2];
    const float cc = (cx * cx + cy * cy) + cz * cz;
    __syncthreads();

    unsigned long long m1 = ~0ull, m2 = ~0ull, m3 = ~0ull, m4 = ~0ull;
#pragma unroll 4
    for (int i = 0; i < 128; ++i) {
        const int idx = lane + i * 64;
        const float4 q = sp[idx];
        const float dot = (cx * q.x + cy * q.y) + cz * q.z;
        float d2 = (cc + q.w) - (2.0f * dot);
        d2 = d2 + 0.0f;                                   // -0.0 -> +0.0
        union { float f; unsigned u; } cv; cv.f = d2;
        unsigned u = cv.u;
        u = (u & 0x80000000u) ? ~u : (u | 0x80000000u);   // ordered-uint
        const unsigned long long kk =
            ((unsigned long long)u << 32) | (unsigned)idx;
        CACHE_INS(kk, m1, m2, m3, m4);
    }

    float resv = 0.0f;
    for (int j = 0; j < PP; ++j) {
        unsigned long long r = m1;
        DPP_RED_U64(r, <);                       // lane 63 authoritative
        const unsigned long long best = readlane63_u64(r);
        if (lane == j) resv = (float)(unsigned)(best & 0xFFFFFFFFu);
        if (m1 == best) { m1 = m2; m2 = m3; m3 = m4; m4 = ~0ull; }
        if (m1 == ~0ull) {                       // rare exact refill (LDS)
            // global extraction is ascending => keys <= best already taken
            for (int i = 0; i < 128; ++i) {
                const int idx = lane + i * 64;
                const float4 q = sp[idx];
                const float dot = (cx * q.x + cy * q.y) + cz * q.z;
                float d2 = (cc + q.w) - (2.0f * dot);
                d2 = d2 + 0.0f;
                union { float f; unsigned u; } cv; cv.f = d2;
                unsigned u = cv.u;
                u = (u & 0x80000000u) ? ~u : (u | 0x80000000u);
                const unsigned long long kk =
                    ((unsigned long long)u << 32) | (unsigned)idx;
                if (kk > best) CACHE_INS(kk, m1, m2, m3, m4);
            }
        }
    }
    if (lane < PP) out[(size_t)bk * PP + lane] = resv;   // 128 B/wave
}

extern "C" void kernel_launch(void* const* d_in, const int* in_sizes, int n_in,
                              void* d_out, int out_size, void* d_ws, size_t ws_size,
                              hipStream_t stream) {
    const float* pts = (const float*)d_in[0];
    float* out = (float*)d_out;   // f32: [idx 131072 | centers 12288]
    const bool use_ws = ws_size >= (size_t)BB * NN * sizeof(float4);
    float4* wsp = use_ws ? (float4*)d_ws : nullptr;

    fps_kernel<<<BB, 512, 0, stream>>>(pts, out, wsp);
    if (use_ws)
        knn_kernel<true><<<BB * 8, 1024, 0, stream>>>(pts, wsp, out);
    else
        knn_kernel<false><<<BB * 8, 1024, 0, stream>>>(pts, nullptr, out);
}